// Round 5
// baseline (407.960 us; speedup 1.0000x reference)
//
#include <hip/hip_runtime.h>

// RandomEqualize: PIL-style histogram equalization per (batch, channel).
// Input: float32 (64,3,512,512), exact integer values in [0,255].
// N = 192 channels, P = 262144 pixels/channel.
//
// 2-kernel pipeline:
//  K1 (R2's best-measured config): 32-copy bank-strided LDS histogram
//      (32 KB, ds_add conflict-free), BPC_H=4; also packs clamped pixels
//      to u8 (cached stores -> L2/L3). Read-floor-bound (~39 us).
//  K2 (occupancy-tuned): 8-copy LUT (8 KB) + 10 KB total LDS ->
//      6 co-resident blocks/CU (24 waves/CU) with BPC_A=8 / 1536 blocks.
//      uint2 packed reads (8 B/lane), unroll 4, NT float4 stores.
//      Was the latency-bound kernel at 12 waves/CU with 34 KB LDS.

#define NBINS 256
#define BPC_H 4                   // hist blocks per channel  (768 blocks)
#define BPC_A 8                   // apply blocks per channel (1536 blocks)
#define NVEC_H 16384              // float4 packets per hist block (P/BPC_H/4)
#define NVEC2_A 4096              // uint2 packets per apply block (P/BPC_A/8)
#define NCOPY_A 8                 // LUT replicas

typedef float vfloat4 __attribute__((ext_vector_type(4)));

// ---------------- K1: histogram + u8 pack ----------------
__global__ __launch_bounds__(256) void eq_hist_pack_kernel(
    const float* __restrict__ in, unsigned int* __restrict__ pack,
    unsigned int* __restrict__ phist) {
    __shared__ unsigned int lh[NBINS * 32];  // 32 KB, word (bin*32+copy) -> bank=copy
    const int t = threadIdx.x;
    const int copy = t & 31;

    for (int i = t; i < NBINS * 32; i += 256) lh[i] = 0u;
    __syncthreads();

    const size_t basev = (size_t)blockIdx.x * NVEC_H;   // float4 / u32 units
    const float4* vin = (const float4*)in + basev;
    unsigned int* pout = pack + basev;                  // one u32 per 4 pixels

    #pragma unroll 4
    for (int i = t; i < NVEC_H; i += 256) {
        float4 v = vin[i];
        int ix = min(max((int)v.x, 0), 255);
        int iy = min(max((int)v.y, 0), 255);
        int iz = min(max((int)v.z, 0), 255);
        int iw = min(max((int)v.w, 0), 255);
        atomicAdd(&lh[ix * 32 + copy], 1u);   // bank = copy = lane&31: conflict-free
        atomicAdd(&lh[iy * 32 + copy], 1u);
        atomicAdd(&lh[iz * 32 + copy], 1u);
        atomicAdd(&lh[iw * 32 + copy], 1u);
        pout[i] = (unsigned)ix | ((unsigned)iy << 8) |
                  ((unsigned)iz << 16) | ((unsigned)iw << 24);
    }
    __syncthreads();

    // thread t owns bin t; staggered copy index keeps lanes on distinct banks
    unsigned int hsum = 0;
    #pragma unroll
    for (int c = 0; c < 32; ++c) hsum += lh[t * 32 + ((t + c) & 31)];
    phist[(size_t)blockIdx.x * NBINS + t] = hsum;   // partial, no atomics
}

// ---------------- K2: LUT build + apply ----------------
__global__ __launch_bounds__(256, 6) void eq_lut_apply_kernel(
    const unsigned int* __restrict__ pack, const unsigned int* __restrict__ phist,
    float* __restrict__ out, int P) {
    __shared__ float slut[NBINS * NCOPY_A];   // 8 KB, 8x bank-replicated LUT
    __shared__ unsigned int s[NBINS];
    __shared__ int sidx[NBINS];
    const int t = threadIdx.x;
    const int copy = t & (NCOPY_A - 1);
    const int chan = blockIdx.x >> 3;         // BPC_A = 8

    // per-channel hist from BPC_H partials
    unsigned int h = 0;
    const unsigned int* pb = phist + (size_t)chan * BPC_H * NBINS;
    #pragma unroll
    for (int b = 0; b < BPC_H; ++b) h += pb[b * NBINS + t];
    s[t] = h;
    sidx[t] = (h != 0u) ? t : -1;
    __syncthreads();

    // max-reduce: last nonzero bin index
    for (int off = 128; off > 0; off >>= 1) {
        if (t < off) sidx[t] = max(sidx[t], sidx[t + off]);
        __syncthreads();
    }
    const int last_idx = sidx[0];
    const int last_val = (int)s[last_idx];
    const int step = (P - last_val) / 255;

    // Hillis-Steele inclusive scan
    for (int off = 1; off < NBINS; off <<= 1) {
        unsigned int v = (t >= off) ? s[t - off] : 0u;
        __syncthreads();
        s[t] += v;
        __syncthreads();
    }

    float lv;
    if (step == 0) {
        lv = (float)t;   // pass-through: identity LUT
    } else {
        int csp = (t == 0) ? 0 : (int)s[t - 1];
        lv = (float)min(max((csp + (step >> 1)) / step, 0), 255);
    }
    #pragma unroll
    for (int c = 0; c < NCOPY_A; ++c)
        slut[t * NCOPY_A + ((t + c) & (NCOPY_A - 1))] = lv;  // ~2 lanes/bank
    __syncthreads();

    // apply: uint2 packed pixels (8/iter), 8-replica LUT gather, NT stores
    const size_t base2 = (size_t)blockIdx.x * NVEC2_A;        // uint2 units
    const uint2* pin = (const uint2*)pack + base2;
    vfloat4* vout = (vfloat4*)out + base2 * 2;                // 2 float4 per uint2

    #pragma unroll 4
    for (int i = t; i < NVEC2_A; i += 256) {
        uint2 p = pin[i];
        vfloat4 r0, r1;
        r0.x = slut[(p.x & 255u) * NCOPY_A + copy];
        r0.y = slut[((p.x >> 8) & 255u) * NCOPY_A + copy];
        r0.z = slut[((p.x >> 16) & 255u) * NCOPY_A + copy];
        r0.w = slut[(p.x >> 24) * NCOPY_A + copy];
        r1.x = slut[(p.y & 255u) * NCOPY_A + copy];
        r1.y = slut[((p.y >> 8) & 255u) * NCOPY_A + copy];
        r1.z = slut[((p.y >> 16) & 255u) * NCOPY_A + copy];
        r1.w = slut[(p.y >> 24) * NCOPY_A + copy];
        __builtin_nontemporal_store(r0, &vout[2 * i]);
        __builtin_nontemporal_store(r1, &vout[2 * i + 1]);
    }
}

extern "C" void kernel_launch(void* const* d_in, const int* in_sizes, int n_in,
                              void* d_out, int out_size, void* d_ws, size_t ws_size,
                              hipStream_t stream) {
    const float* img = (const float*)d_in[0];
    float* out = (float*)d_out;

    const int P = 512 * 512;        // pixels per channel
    const int total = in_sizes[0];  // 64*3*512*512 elements
    const int N = total / P;        // 192 channels

    // ws layout: packed u8 pixels (total bytes) | partial hists (768 KB)
    unsigned int* pack  = (unsigned int*)d_ws;
    unsigned int* phist = (unsigned int*)((char*)d_ws + (size_t)total);

    eq_hist_pack_kernel<<<N * BPC_H, 256, 0, stream>>>(img, pack, phist);
    eq_lut_apply_kernel<<<N * BPC_A, 256, 0, stream>>>(pack, phist, out, P);
}

// Round 6
// 341.779 us; speedup vs baseline: 1.1936x; 1.1936x over previous
//
#include <hip/hip_runtime.h>

// RandomEqualize: PIL-style histogram equalization per (batch, channel).
// Input: float32 (64,3,512,512), exact integer values in [0,255].
// N = 192 channels, P = 262144 pixels/channel.
//
// 2-kernel pipeline:
//  K1: 32-copy bank-strided LDS histogram (32 KB, ds_add conflict-free),
//      BPC_H=4. NT input loads (input is dead after K1 -> keep L3 for pack).
//      Packs clamped pixels to u8 (cached stores -> L3). Read-floor ~45 us.
//  K2: 16-replica LUT (16 KB, ~2-way gather = free), BPC_A=16 (3072 blocks)
//      + launch_bounds(256,8) -> 8 blocks/CU = 32 waves/CU. u32 pack reads,
//      ONE coalesced NT float4 store per lane per iter (R5's strided dual
//      store was the -55us regression). Floor ~35 us.

#define NBINS 256
#define BPC_H 4                   // hist blocks per channel  (768 blocks)
#define BPC_A 16                  // apply blocks per channel (3072 blocks)
#define NVEC_H 16384              // float4 packets per hist block (P/BPC_H/4)
#define NVEC_A 4096               // u32 packets per apply block  (P/BPC_A/4)
#define NCOPY_A 16                // LUT replicas

typedef float vfloat4 __attribute__((ext_vector_type(4)));

// ---------------- K1: histogram + u8 pack ----------------
__global__ __launch_bounds__(256) void eq_hist_pack_kernel(
    const float* __restrict__ in, unsigned int* __restrict__ pack,
    unsigned int* __restrict__ phist) {
    __shared__ unsigned int lh[NBINS * 32];  // 32 KB, word (bin*32+copy) -> bank=copy
    const int t = threadIdx.x;
    const int copy = t & 31;

    for (int i = t; i < NBINS * 32; i += 256) lh[i] = 0u;
    __syncthreads();

    const size_t basev = (size_t)blockIdx.x * NVEC_H;   // float4 / u32 units
    const vfloat4* vin = (const vfloat4*)in + basev;
    unsigned int* pout = pack + basev;                  // one u32 per 4 pixels

    #pragma unroll 4
    for (int i = t; i < NVEC_H; i += 256) {
        vfloat4 v = __builtin_nontemporal_load(&vin[i]);  // dead after K1
        int ix = min(max((int)v.x, 0), 255);
        int iy = min(max((int)v.y, 0), 255);
        int iz = min(max((int)v.z, 0), 255);
        int iw = min(max((int)v.w, 0), 255);
        atomicAdd(&lh[ix * 32 + copy], 1u);   // bank = copy = lane&31: conflict-free
        atomicAdd(&lh[iy * 32 + copy], 1u);
        atomicAdd(&lh[iz * 32 + copy], 1u);
        atomicAdd(&lh[iw * 32 + copy], 1u);
        pout[i] = (unsigned)ix | ((unsigned)iy << 8) |
                  ((unsigned)iz << 16) | ((unsigned)iw << 24);
    }
    __syncthreads();

    // thread t owns bin t; staggered copy index keeps lanes on distinct banks
    unsigned int hsum = 0;
    #pragma unroll
    for (int c = 0; c < 32; ++c) hsum += lh[t * 32 + ((t + c) & 31)];
    phist[(size_t)blockIdx.x * NBINS + t] = hsum;   // partial, no atomics
}

// ---------------- K2: LUT build + apply ----------------
__global__ __launch_bounds__(256, 8) void eq_lut_apply_kernel(
    const unsigned int* __restrict__ pack, const unsigned int* __restrict__ phist,
    float* __restrict__ out, int P) {
    __shared__ float slut[NBINS * NCOPY_A];   // 16 KB, 16x bank-replicated LUT
    __shared__ unsigned int s[NBINS];
    __shared__ int sidx[NBINS];
    const int t = threadIdx.x;
    const int copy = t & (NCOPY_A - 1);
    const int chan = blockIdx.x >> 4;         // BPC_A = 16

    // per-channel hist from BPC_H partials
    unsigned int h = 0;
    const unsigned int* pb = phist + (size_t)chan * BPC_H * NBINS;
    #pragma unroll
    for (int b = 0; b < BPC_H; ++b) h += pb[b * NBINS + t];
    s[t] = h;
    sidx[t] = (h != 0u) ? t : -1;
    __syncthreads();

    // max-reduce: last nonzero bin index
    for (int off = 128; off > 0; off >>= 1) {
        if (t < off) sidx[t] = max(sidx[t], sidx[t + off]);
        __syncthreads();
    }
    const int last_idx = sidx[0];
    const int last_val = (int)s[last_idx];
    const int step = (P - last_val) / 255;

    // Hillis-Steele inclusive scan
    for (int off = 1; off < NBINS; off <<= 1) {
        unsigned int v = (t >= off) ? s[t - off] : 0u;
        __syncthreads();
        s[t] += v;
        __syncthreads();
    }

    float lv;
    if (step == 0) {
        lv = (float)t;   // pass-through: identity LUT
    } else {
        int csp = (t == 0) ? 0 : (int)s[t - 1];
        lv = (float)min(max((csp + (step >> 1)) / step, 0), 255);
    }
    #pragma unroll
    for (int c = 0; c < NCOPY_A; ++c)
        slut[t * NCOPY_A + ((t + c) & (NCOPY_A - 1))] = lv;  // 2-way: free
    __syncthreads();

    // apply: u32 packed pixels, 16-replica LUT gather, coalesced NT stores
    const size_t basev = (size_t)blockIdx.x * NVEC_A;   // u32 / float4 units
    const unsigned int* pin = pack + basev;             // u8 pixels, L3-resident
    vfloat4* vout = (vfloat4*)out + basev;

    #pragma unroll 4
    for (int i = t; i < NVEC_A; i += 256) {
        unsigned int p = pin[i];
        vfloat4 r;
        r.x = slut[(p & 255u) * NCOPY_A + copy];
        r.y = slut[((p >> 8) & 255u) * NCOPY_A + copy];
        r.z = slut[((p >> 16) & 255u) * NCOPY_A + copy];
        r.w = slut[(p >> 24) * NCOPY_A + copy];
        __builtin_nontemporal_store(r, &vout[i]);   // lane-consecutive: coalesced
    }
}

extern "C" void kernel_launch(void* const* d_in, const int* in_sizes, int n_in,
                              void* d_out, int out_size, void* d_ws, size_t ws_size,
                              hipStream_t stream) {
    const float* img = (const float*)d_in[0];
    float* out = (float*)d_out;

    const int P = 512 * 512;        // pixels per channel
    const int total = in_sizes[0];  // 64*3*512*512 elements
    const int N = total / P;        // 192 channels

    // ws layout: packed u8 pixels (total bytes) | partial hists (768 KB)
    unsigned int* pack  = (unsigned int*)d_ws;
    unsigned int* phist = (unsigned int*)((char*)d_ws + (size_t)total);

    eq_hist_pack_kernel<<<N * BPC_H, 256, 0, stream>>>(img, pack, phist);
    eq_lut_apply_kernel<<<N * BPC_A, 256, 0, stream>>>(pack, phist, out, P);
}